// Round 4
// baseline (332.241 us; speedup 1.0000x reference)
//
#include <hip/hip_runtime.h>
#include <math.h>

#define HPX 128
#define WPX 128
#define HW  16384          // H*W
#define CCH 16             // channels
#define NLINES 81920       // 5 * H * W
#define NPTS 32
#define LOI_SIZE (NLINES * 512)   // 41,943,040 floats
#define SORT_N 4096        // hard bound: strict 3x3 NMS survivors <= 4096

typedef float vfloat4 __attribute__((ext_vector_type(4)));   // native vec for nt-store

// workspace layout (bytes)
#define FEAT_T_OFF 0                             // 1,048,576
#define LINES_OFF  1048576                       // 81920*16 = 1,310,720
#define KEYS_OFF   (1048576 + 1310720)           // 4096*8 = 32,768
#define CTR_OFF    (KEYS_OFF + 32768)            // 4

// prep kernel block ranges
#define TP_BLOCKS    1024   // transpose: 262144 threads
#define LINE_BLOCKS  320    // lines: 81920 threads
#define NMS_BLOCKS   64     // nms: 16384 threads
#define PREP_BLOCKS  (TP_BLOCKS + LINE_BLOCKS + NMS_BLOCKS)

// ---------------------------------------------------------------------------
// Fused prep: [0,1024) transpose feat (C,H,W)->(H*W,C); [1024,1344) line
// endpoint decode (all trig); [1344,1408) 3x3 NMS + survivor compaction.
// key = float_bits(val)<<32 | (0xFFFFFFFF - idx): descending u64 order ==
// descending value, ascending index tie-break (matches jax.lax.top_k).
// ---------------------------------------------------------------------------
__global__ __launch_bounds__(256) void prep_kernel(
        const float* __restrict__ feat, float* __restrict__ feat_t,
        const float* __restrict__ md,
        const float* __restrict__ dis,
        const float* __restrict__ res,
        float4* __restrict__ lines,
        const float* __restrict__ jloc,
        unsigned long long* __restrict__ keys,
        unsigned int* __restrict__ ctr) {
    int blk = blockIdx.x;
    if (blk < TP_BLOCKS) {
        int tid = blk * 256 + threadIdx.x;       // 0 .. 262143
        int pix = tid >> 4;
        int c   = tid & 15;
        feat_t[tid] = feat[c * HW + pix];
    } else if (blk < TP_BLOCKS + LINE_BLOCKS) {
        int line = (blk - TP_BLOCKS) * 256 + threadIdx.x;   // 0 .. 81919
        int r    = line >> 14;                   // 0..4
        int pix  = line & (HW - 1);
        int y0i  = pix >> 7, x0i = pix & 127;

        float md0 = md[pix], md1 = md[HW + pix], md2 = md[2 * HW + pix];
        float dv  = dis[pix], rv = res[pix];

        float dist = fminf(fmaxf(dv + rv * ((float)r - 2.0f), 0.0f), 1.0f);
        float d5   = dist * 5.0f;
        float md_un = (md0 - 0.5f) * 6.28318530717958647692f;
        float cs = cosf(md_un), ss = sinf(md_un);
        float y_st = tanf(md1 * 1.57079632679489661923f);
        float y_ed = tanf(-md2 * 1.57079632679489661923f);

        float x0f = (float)x0i, y0f = (float)y0i;
        float4 ep;
        ep.x = fminf(fmaxf((cs - ss * y_st) * d5 + x0f, 0.0f), 127.0f);  // xs
        ep.y = fminf(fmaxf((ss + cs * y_st) * d5 + y0f, 0.0f), 127.0f);  // ys
        ep.z = fminf(fmaxf((cs - ss * y_ed) * d5 + x0f, 0.0f), 127.0f);  // xe
        ep.w = fminf(fmaxf((ss + cs * y_ed) * d5 + y0f, 0.0f), 127.0f);  // ye
        lines[line] = ep;
    } else {
        int pix = (blk - TP_BLOCKS - LINE_BLOCKS) * 256 + threadIdx.x;
        int y = pix >> 7, x = pix & 127;
        float a = jloc[pix];
        float m = a;
        #pragma unroll
        for (int dy = -1; dy <= 1; dy++) {
            #pragma unroll
            for (int dx = -1; dx <= 1; dx++) {
                int yy = y + dy, xx = x + dx;
                if (yy >= 0 && yy < HPX && xx >= 0 && xx < WPX) {
                    m = fmaxf(m, jloc[yy * WPX + xx]);
                }
            }
        }
        if (a == m && a > 0.0f) {
            unsigned int slot = atomicAdd(ctr, 1u);
            if (slot < SORT_N) {
                unsigned int bits = __float_as_uint(a);
                keys[slot] = ((unsigned long long)bits << 32)
                           | (unsigned long long)(0xFFFFFFFFu - (unsigned int)pix);
            }
        }
    }
}

// ---------------------------------------------------------------------------
// Rank-select top-k: each thread owns <=4 survivor keys; rank = count of
// strictly-greater keys (all distinct => ranks unique & complete); rank<topk
// writes output slot `rank` directly. No sort, no barriers in the hot loop.
// ---------------------------------------------------------------------------
__global__ __launch_bounds__(1024) void select_topk(
        const unsigned long long* __restrict__ keys_g,
        const unsigned int* __restrict__ ctr,
        const float* __restrict__ joff,
        float* __restrict__ junc, float* __restrict__ scores, int topk) {
    __shared__ unsigned long long sk[SORT_N];    // 32 KB
    int t = threadIdx.x;
    int n = (int)min(ctr[0], (unsigned int)SORT_N);

    for (int i = t; i < n; i += 1024) sk[i] = keys_g[i];
    __syncthreads();

    unsigned long long my[4];
    int rank[4];
    #pragma unroll
    for (int q = 0; q < 4; q++) {
        int i = t + q * 1024;
        my[q] = (i < n) ? sk[i] : 0ull;
        rank[q] = 0;
    }

    for (int j = 0; j < n; j++) {
        unsigned long long kj = sk[j];           // uniform j -> LDS broadcast
        #pragma unroll
        for (int q = 0; q < 4; q++) rank[q] += (kj > my[q]) ? 1 : 0;
    }

    #pragma unroll
    for (int q = 0; q < 4; q++) {
        int i = t + q * 1024;
        if (i < n && rank[q] < topk) {
            unsigned long long kk = my[q];
            float val = __uint_as_float((unsigned int)(kk >> 32));
            unsigned int idx = 0xFFFFFFFFu - (unsigned int)(kk & 0xFFFFFFFFull);
            float xo = joff[idx];                // joff[0][idx]
            float yo = joff[HW + idx];           // joff[1][idx]
            int r = rank[q];
            junc[2 * r]     = (float)(idx & 127) + xo + 0.5f;  // x
            junc[2 * r + 1] = (float)(idx >> 7)  + yo + 0.5f;  // y
            scores[r] = val;
        }
    }
}

// ---------------------------------------------------------------------------
// LOI: one thread = (line, k-quad). 4 sample points x 16 channels;
// 16 coalesced nontemporal float4 stores. No trig (reads lines[]).
// ---------------------------------------------------------------------------
__global__ __launch_bounds__(256) void loi_kernel(
        const float4* __restrict__ lines,
        const float* __restrict__ feat_t,
        float* __restrict__ out) {
    int tid  = blockIdx.x * 256 + threadIdx.x;   // 0 .. 655,359
    int kq   = tid & 7;
    int line = tid >> 3;

    float4 ep = lines[line];
    float v[64];                                  // [c][p], static-indexed

    #pragma unroll
    for (int p = 0; p < 4; ++p) {
        int k = kq * 4 + p;
        float tk = (float)k * (1.0f / 31.0f);
        float px = ep.x * tk + ep.z * (1.0f - tk) - 0.5f;
        float py = ep.y * tk + ep.w * (1.0f - tk) - 0.5f;

        float px0 = fminf(fmaxf(floorf(px), 0.0f), 127.0f);
        float py0 = fminf(fmaxf(floorf(py), 0.0f), 127.0f);
        float px1 = fminf(px0 + 1.0f, 127.0f);
        float py1 = fminf(py0 + 1.0f, 127.0f);

        float wx1 = px - px0, wx0 = px1 - px;
        float wy1 = py - py0, wy0 = py1 - py;
        float w00 = wy0 * wx0, w01 = wy0 * wx1;
        float w10 = wy1 * wx0, w11 = wy1 * wx1;

        int b00 = (((int)py0) * WPX + (int)px0) * 4;   // float4 index
        int b01 = (((int)py0) * WPX + (int)px1) * 4;
        int b10 = (((int)py1) * WPX + (int)px0) * 4;
        int b11 = (((int)py1) * WPX + (int)px1) * 4;

        const float4* f4 = (const float4*)feat_t;
        #pragma unroll
        for (int cq = 0; cq < 4; ++cq) {
            float4 a = f4[b00 + cq], b = f4[b01 + cq];
            float4 c = f4[b10 + cq], d = f4[b11 + cq];
            v[(cq * 4 + 0) * 4 + p] = a.x * w00 + b.x * w01 + c.x * w10 + d.x * w11;
            v[(cq * 4 + 1) * 4 + p] = a.y * w00 + b.y * w01 + c.y * w10 + d.y * w11;
            v[(cq * 4 + 2) * 4 + p] = a.z * w00 + b.z * w01 + c.z * w10 + d.z * w11;
            v[(cq * 4 + 3) * 4 + p] = a.w * w00 + b.w * w01 + c.w * w10 + d.w * w11;
        }
    }

    float* ob = out + (size_t)line * 512 + kq * 4;
    #pragma unroll
    for (int c = 0; c < 16; ++c) {
        vfloat4 st = { v[c * 4 + 0], v[c * 4 + 1], v[c * 4 + 2], v[c * 4 + 3] };
        __builtin_nontemporal_store(st, (vfloat4*)(ob + c * 32));
    }
}

extern "C" void kernel_launch(void* const* d_in, const int* in_sizes, int n_in,
                              void* d_out, int out_size, void* d_ws, size_t ws_size,
                              hipStream_t stream) {
    const float* md   = (const float*)d_in[0];
    const float* dis  = (const float*)d_in[1];
    const float* res  = (const float*)d_in[2];
    const float* feat = (const float*)d_in[3];
    const float* jloc = (const float*)d_in[4];
    const float* joff = (const float*)d_in[5];
    int topk = (out_size - LOI_SIZE) / 3;

    char* ws = (char*)d_ws;
    float* feat_t             = (float*)(ws + FEAT_T_OFF);
    float4* lines             = (float4*)(ws + LINES_OFF);
    unsigned long long* keys  = (unsigned long long*)(ws + KEYS_OFF);
    unsigned int* ctr         = (unsigned int*)(ws + CTR_OFF);

    float* out    = (float*)d_out;
    float* junc   = out + LOI_SIZE;
    float* scores = junc + 2 * topk;

    (void)hipMemsetAsync(ctr, 0, 4, stream);     // survivor counter only

    prep_kernel<<<PREP_BLOCKS, 256, 0, stream>>>(feat, feat_t, md, dis, res,
                                                 lines, jloc, keys, ctr);
    select_topk<<<1, 1024, 0, stream>>>(keys, ctr, joff, junc, scores, topk);
    loi_kernel <<<(NLINES * 8) / 256, 256, 0, stream>>>(lines, feat_t, out);
}

// Round 5
// 230.254 us; speedup vs baseline: 1.4429x; 1.4429x over previous
//
#include <hip/hip_runtime.h>
#include <math.h>

#define HPX 128
#define WPX 128
#define HW  16384          // H*W
#define CCH 16             // channels
#define NLINES 81920       // 5 * H * W
#define NPTS 32
#define LOI_SIZE (NLINES * 512)   // 41,943,040 floats
#define SORT_N 4096        // hard bound: strict 3x3 NMS survivors <= 4096
#define NBINS 4096
#define CAND 1024

typedef float vfloat4 __attribute__((ext_vector_type(4)));   // native vec for nt-store

// workspace layout (bytes)
#define FEAT_T_OFF 0                             // 1,048,576
#define LINES_OFF  1048576                       // 81920*16 = 1,310,720
#define KEYS_OFF   (1048576 + 1310720)           // 4096*8 = 32,768
#define HIST_OFF   (KEYS_OFF + 32768)            // 4096*4 = 16,384
#define CTR_OFF    (HIST_OFF + 16384)            // 4

// prep kernel block ranges
#define TP_BLOCKS    1024   // transpose: 262144 threads
#define LINE_BLOCKS  320    // lines: 81920 threads
#define NMS_BLOCKS   64     // nms: 16384 threads
#define PREP_BLOCKS  (TP_BLOCKS + LINE_BLOCKS + NMS_BLOCKS)

// ---------------------------------------------------------------------------
// Fused prep: [0,1024) transpose feat (C,H,W)->(H*W,C); [1024,1344) line
// endpoint decode (all trig); [1344,1408) 3x3 NMS + survivor compaction +
// 4096-bin value histogram (for topk threshold).
// key = float_bits(val)<<32 | (0xFFFFFFFF - idx): descending u64 order ==
// descending value, ascending index tie-break (matches jax.lax.top_k).
// ---------------------------------------------------------------------------
__global__ __launch_bounds__(256) void prep_kernel(
        const float* __restrict__ feat, float* __restrict__ feat_t,
        const float* __restrict__ md,
        const float* __restrict__ dis,
        const float* __restrict__ res,
        float4* __restrict__ lines,
        const float* __restrict__ jloc,
        unsigned long long* __restrict__ keys,
        unsigned int* __restrict__ hist,
        unsigned int* __restrict__ ctr) {
    int blk = blockIdx.x;
    if (blk < TP_BLOCKS) {
        int tid = blk * 256 + threadIdx.x;       // 0 .. 262143
        int pix = tid >> 4;
        int c   = tid & 15;
        feat_t[tid] = feat[c * HW + pix];
    } else if (blk < TP_BLOCKS + LINE_BLOCKS) {
        int line = (blk - TP_BLOCKS) * 256 + threadIdx.x;   // 0 .. 81919
        int r    = line >> 14;                   // 0..4
        int pix  = line & (HW - 1);
        int y0i  = pix >> 7, x0i = pix & 127;

        float md0 = md[pix], md1 = md[HW + pix], md2 = md[2 * HW + pix];
        float dv  = dis[pix], rv = res[pix];

        float dist = fminf(fmaxf(dv + rv * ((float)r - 2.0f), 0.0f), 1.0f);
        float d5   = dist * 5.0f;
        float md_un = (md0 - 0.5f) * 6.28318530717958647692f;
        float cs = cosf(md_un), ss = sinf(md_un);
        float y_st = tanf(md1 * 1.57079632679489661923f);
        float y_ed = tanf(-md2 * 1.57079632679489661923f);

        float x0f = (float)x0i, y0f = (float)y0i;
        float4 ep;
        ep.x = fminf(fmaxf((cs - ss * y_st) * d5 + x0f, 0.0f), 127.0f);  // xs
        ep.y = fminf(fmaxf((ss + cs * y_st) * d5 + y0f, 0.0f), 127.0f);  // ys
        ep.z = fminf(fmaxf((cs - ss * y_ed) * d5 + x0f, 0.0f), 127.0f);  // xe
        ep.w = fminf(fmaxf((ss + cs * y_ed) * d5 + y0f, 0.0f), 127.0f);  // ye
        lines[line] = ep;
    } else {
        int pix = (blk - TP_BLOCKS - LINE_BLOCKS) * 256 + threadIdx.x;
        int y = pix >> 7, x = pix & 127;
        float a = jloc[pix];
        float m = a;
        #pragma unroll
        for (int dy = -1; dy <= 1; dy++) {
            #pragma unroll
            for (int dx = -1; dx <= 1; dx++) {
                int yy = y + dy, xx = x + dx;
                if (yy >= 0 && yy < HPX && xx >= 0 && xx < WPX) {
                    m = fmaxf(m, jloc[yy * WPX + xx]);
                }
            }
        }
        if (a == m && a > 0.0f) {
            unsigned int slot = atomicAdd(ctr, 1u);
            if (slot < SORT_N) {
                unsigned int bits = __float_as_uint(a);
                keys[slot] = ((unsigned long long)bits << 32)
                           | (unsigned long long)(0xFFFFFFFFu - (unsigned int)pix);
            }
            int bin = min(NBINS - 1, (int)(a * (float)NBINS));
            atomicAdd(&hist[bin], 1u);
        }
    }
}

// ---------------------------------------------------------------------------
// Single-block top-k:
//   1) suffix-scan 4096-bin histogram (12 Hillis-Steele passes)
//   2) threshold bin T: suffix[T] >= topk > suffix[T+1]  => candidates with
//      bin >= T number >= topk but only ~topk+bin-T population (~350)
//   3) compact candidates to LDS
//   4) rank-select: thread t owns cand[t]; rank = #(strictly greater keys),
//      j-loop unrolled x8 over zero-padded array => 8 outstanding ds_reads
//      (the R4 lesson: a non-unrolled LDS loop is 160 cyc/iter latency-bound)
//   5) rank < topk writes output slot `rank` directly (keys distinct).
// ---------------------------------------------------------------------------
__global__ __launch_bounds__(1024) void select_topk(
        const unsigned long long* __restrict__ keys_g,
        const unsigned int* __restrict__ ctr,
        const unsigned int* __restrict__ hist,
        const float* __restrict__ joff,
        float* __restrict__ junc, float* __restrict__ scores, int topk) {
    __shared__ unsigned int h[NBINS];                // 16 KB
    __shared__ unsigned long long cand[CAND + 8];    // 8 KB + pad
    __shared__ unsigned int scount;
    __shared__ int Ts;
    int t = threadIdx.x;

    #pragma unroll
    for (int r = 0; r < 4; r++) h[t + r * 1024] = hist[t + r * 1024];
    if (t == 0) { scount = 0; Ts = 0; }
    __syncthreads();

    // suffix sum: h[b] := sum_{b' >= b} h[b']
    for (int off = 1; off < NBINS; off <<= 1) {
        unsigned int v[4];
        #pragma unroll
        for (int r = 0; r < 4; r++) {
            int i = t + r * 1024;
            v[r] = (i + off < NBINS) ? h[i + off] : 0u;
        }
        __syncthreads();
        #pragma unroll
        for (int r = 0; r < 4; r++) h[t + r * 1024] += v[r];
        __syncthreads();
    }

    // threshold bin T (unique crossing)
    #pragma unroll
    for (int r = 0; r < 4; r++) {
        int b = t + r * 1024;
        unsigned int sb = h[b];
        unsigned int sn = (b + 1 < NBINS) ? h[b + 1] : 0u;
        if (sb >= (unsigned int)topk && sn < (unsigned int)topk) Ts = b;
    }
    __syncthreads();
    int T = Ts;

    // compact candidates (bin >= T)
    int n = (int)min(ctr[0], (unsigned int)SORT_N);
    for (int i = t; i < n; i += 1024) {
        unsigned long long kk = keys_g[i];
        float val = __uint_as_float((unsigned int)(kk >> 32));
        int bin = min(NBINS - 1, (int)(val * (float)NBINS));
        if (bin >= T) {
            unsigned int p = atomicAdd(&scount, 1u);
            if (p < CAND) cand[p] = kk;
        }
    }
    __syncthreads();
    int sc = (int)min(scount, (unsigned int)CAND);
    int padded = (sc + 7) & ~7;
    if (t >= sc && t < padded + 8) cand[t] = 0ull;   // zero pad (never > any key)
    __syncthreads();

    // rank-select, unrolled x8
    unsigned long long my = (t < sc) ? cand[t] : 0ull;
    int rank = 0;
    for (int j = 0; j < padded; j += 8) {
        unsigned long long kj[8];
        #pragma unroll
        for (int u = 0; u < 8; u++) kj[u] = cand[j + u];
        #pragma unroll
        for (int u = 0; u < 8; u++) rank += (kj[u] > my) ? 1 : 0;
    }

    if (t < sc && rank < topk) {
        float val = __uint_as_float((unsigned int)(my >> 32));
        unsigned int idx = 0xFFFFFFFFu - (unsigned int)(my & 0xFFFFFFFFull);
        float xo = joff[idx];                // joff[0][idx]
        float yo = joff[HW + idx];           // joff[1][idx]
        junc[2 * rank]     = (float)(idx & 127) + xo + 0.5f;  // x
        junc[2 * rank + 1] = (float)(idx >> 7)  + yo + 0.5f;  // y
        scores[rank] = val;
    }
}

// ---------------------------------------------------------------------------
// LOI: one thread = (line, k-quad). 4 sample points x 16 channels;
// 16 coalesced nontemporal float4 stores. No trig (reads lines[]).
// ---------------------------------------------------------------------------
__global__ __launch_bounds__(256) void loi_kernel(
        const float4* __restrict__ lines,
        const float* __restrict__ feat_t,
        float* __restrict__ out) {
    int tid  = blockIdx.x * 256 + threadIdx.x;   // 0 .. 655,359
    int kq   = tid & 7;
    int line = tid >> 3;

    float4 ep = lines[line];
    float v[64];                                  // [c][p], static-indexed

    #pragma unroll
    for (int p = 0; p < 4; ++p) {
        int k = kq * 4 + p;
        float tk = (float)k * (1.0f / 31.0f);
        float px = ep.x * tk + ep.z * (1.0f - tk) - 0.5f;
        float py = ep.y * tk + ep.w * (1.0f - tk) - 0.5f;

        float px0 = fminf(fmaxf(floorf(px), 0.0f), 127.0f);
        float py0 = fminf(fmaxf(floorf(py), 0.0f), 127.0f);
        float px1 = fminf(px0 + 1.0f, 127.0f);
        float py1 = fminf(py0 + 1.0f, 127.0f);

        float wx1 = px - px0, wx0 = px1 - px;
        float wy1 = py - py0, wy0 = py1 - py;
        float w00 = wy0 * wx0, w01 = wy0 * wx1;
        float w10 = wy1 * wx0, w11 = wy1 * wx1;

        int b00 = (((int)py0) * WPX + (int)px0) * 4;   // float4 index
        int b01 = (((int)py0) * WPX + (int)px1) * 4;
        int b10 = (((int)py1) * WPX + (int)px0) * 4;
        int b11 = (((int)py1) * WPX + (int)px1) * 4;

        const float4* f4 = (const float4*)feat_t;
        #pragma unroll
        for (int cq = 0; cq < 4; ++cq) {
            float4 a = f4[b00 + cq], b = f4[b01 + cq];
            float4 c = f4[b10 + cq], d = f4[b11 + cq];
            v[(cq * 4 + 0) * 4 + p] = a.x * w00 + b.x * w01 + c.x * w10 + d.x * w11;
            v[(cq * 4 + 1) * 4 + p] = a.y * w00 + b.y * w01 + c.y * w10 + d.y * w11;
            v[(cq * 4 + 2) * 4 + p] = a.z * w00 + b.z * w01 + c.z * w10 + d.z * w11;
            v[(cq * 4 + 3) * 4 + p] = a.w * w00 + b.w * w01 + c.w * w10 + d.w * w11;
        }
    }

    float* ob = out + (size_t)line * 512 + kq * 4;
    #pragma unroll
    for (int c = 0; c < 16; ++c) {
        vfloat4 st = { v[c * 4 + 0], v[c * 4 + 1], v[c * 4 + 2], v[c * 4 + 3] };
        __builtin_nontemporal_store(st, (vfloat4*)(ob + c * 32));
    }
}

extern "C" void kernel_launch(void* const* d_in, const int* in_sizes, int n_in,
                              void* d_out, int out_size, void* d_ws, size_t ws_size,
                              hipStream_t stream) {
    const float* md   = (const float*)d_in[0];
    const float* dis  = (const float*)d_in[1];
    const float* res  = (const float*)d_in[2];
    const float* feat = (const float*)d_in[3];
    const float* jloc = (const float*)d_in[4];
    const float* joff = (const float*)d_in[5];
    int topk = (out_size - LOI_SIZE) / 3;

    char* ws = (char*)d_ws;
    float* feat_t             = (float*)(ws + FEAT_T_OFF);
    float4* lines             = (float4*)(ws + LINES_OFF);
    unsigned long long* keys  = (unsigned long long*)(ws + KEYS_OFF);
    unsigned int* hist        = (unsigned int*)(ws + HIST_OFF);
    unsigned int* ctr         = (unsigned int*)(ws + CTR_OFF);

    float* out    = (float*)d_out;
    float* junc   = out + LOI_SIZE;
    float* scores = junc + 2 * topk;

    (void)hipMemsetAsync(ws + HIST_OFF, 0, NBINS * 4 + 4, stream);  // hist + ctr

    prep_kernel<<<PREP_BLOCKS, 256, 0, stream>>>(feat, feat_t, md, dis, res,
                                                 lines, jloc, keys, hist, ctr);
    select_topk<<<1, 1024, 0, stream>>>(keys, ctr, hist, joff, junc, scores, topk);
    loi_kernel <<<(NLINES * 8) / 256, 256, 0, stream>>>(lines, feat_t, out);
}